// Round 5
// baseline (310.782 us; speedup 1.0000x reference)
//
#include <hip/hip_runtime.h>
#include <hip/hip_fp16.h>
#include <math.h>

#define NNODES 100000
#define NEG_SLOPE 0.2f
#define FIN 500
#define KP 512     // padded K
#define HID 128    // heads*hidden
#define NH 4

typedef __attribute__((ext_vector_type(8))) short short8v;
typedef __attribute__((ext_vector_type(4))) float f32x4;

__device__ __forceinline__ float lrelu(float x) { return x > 0.f ? x : NEG_SLOPE * x; }

__device__ __forceinline__ float sel4(float a0, float a1, float a2, float a3, int h) {
  float r = a0;
  r = (h == 1) ? a1 : r;
  r = (h == 2) ? a2 : r;
  r = (h == 3) ? a3 : r;
  return r;
}

__device__ __forceinline__ unsigned short f32_to_bf16_rn(float f) {
  unsigned u = __float_as_uint(f);
  unsigned r = u + 0x7fffu + ((u >> 16) & 1u);
  return (unsigned short)(r >> 16);
}
__device__ __forceinline__ float bf16_to_f32(unsigned short h) {
  return __uint_as_float(((unsigned)h) << 16);
}

// swizzled LDS offset (in shorts) for [row][k] tile, row stride 32 shorts, 16B slots
__device__ __forceinline__ int lds_off(int row, int slot8) {
  return row * 32 + ((slot8 ^ ((row >> 1) & 3)) << 3);
}

// ---------------- W1 -> transposed bf16 hi/lo [128][512] ----------------
__global__ __launch_bounds__(256) void convert_w1_kernel(const float* __restrict__ W1,
                                                         short* __restrict__ BhT,
                                                         short* __restrict__ BlT) {
  int idx = blockIdx.x * 256 + threadIdx.x;  // 65536
  int n = idx >> 9, k = idx & 511;
  float v = (k < FIN) ? W1[k * HID + n] : 0.f;
  unsigned short hb = f32_to_bf16_rn(v);
  float lo = v - bf16_to_f32(hb);
  BhT[n * KP + k] = (short)hb;
  BlT[n * KP + k] = (short)f32_to_bf16_rn(lo);
}

// ---------------- GEMM1: pipelined split-bf16 MFMA, B direct from L2 ----------------
__global__ __launch_bounds__(256, 2) void gemm1_mfma_kernel(const float* __restrict__ A,
                                                            const short* __restrict__ BhT,
                                                            const short* __restrict__ BlT,
                                                            __half* __restrict__ z1h) {
  __shared__ __align__(16) short Ah[2][128 * 32];
  __shared__ __align__(16) short Al[2][128 * 32];
  const int t = threadIdx.x;
  const int bm = blockIdx.x * 128;
  const int wid = t >> 6, lane = t & 63;
  const int wr = wid >> 1, wc = wid & 1;
  const int fr = lane & 15, ko = lane >> 4;
  const int srow = t >> 2, sslot = t & 3;      // staging: rows srow, srow+64; slot sslot
  const int g0 = bm + srow, g1 = bm + srow + 64;

  f32x4 acc[4][4];
#pragma unroll
  for (int i = 0; i < 4; i++)
#pragma unroll
    for (int j = 0; j < 4; j++) acc[i][j] = (f32x4){0.f, 0.f, 0.f, 0.f};

  float ar0[8], ar1[8];
  short8v bh0[4], bl0[4], bh1[4], bl1[4];

#define LOAD_A(K0)                                                                   \
  do {                                                                               \
    int kk = (K0) + sslot * 8;                                                       \
    if (g0 < NNODES && kk + 7 < FIN) {                                               \
      float4 u0 = *(const float4*)&A[(size_t)g0 * FIN + kk];                         \
      float4 u1 = *(const float4*)&A[(size_t)g0 * FIN + kk + 4];                     \
      ar0[0] = u0.x; ar0[1] = u0.y; ar0[2] = u0.z; ar0[3] = u0.w;                    \
      ar0[4] = u1.x; ar0[5] = u1.y; ar0[6] = u1.z; ar0[7] = u1.w;                    \
    } else {                                                                         \
      _Pragma("unroll")                                                              \
      for (int i = 0; i < 8; i++)                                                    \
        ar0[i] = (g0 < NNODES && kk + i < FIN) ? A[(size_t)g0 * FIN + kk + i] : 0.f; \
    }                                                                                \
    if (g1 < NNODES && kk + 7 < FIN) {                                               \
      float4 u0 = *(const float4*)&A[(size_t)g1 * FIN + kk];                         \
      float4 u1 = *(const float4*)&A[(size_t)g1 * FIN + kk + 4];                     \
      ar1[0] = u0.x; ar1[1] = u0.y; ar1[2] = u0.z; ar1[3] = u0.w;                    \
      ar1[4] = u1.x; ar1[5] = u1.y; ar1[6] = u1.z; ar1[7] = u1.w;                    \
    } else {                                                                         \
      _Pragma("unroll")                                                              \
      for (int i = 0; i < 8; i++)                                                    \
        ar1[i] = (g1 < NNODES && kk + i < FIN) ? A[(size_t)g1 * FIN + kk + i] : 0.f; \
    }                                                                                \
  } while (0)

#define CONV_A(BUF)                                                 \
  do {                                                              \
    short8v hv0, lv0, hv1, lv1;                                     \
    _Pragma("unroll")                                               \
    for (int i = 0; i < 8; i++) {                                   \
      unsigned short hb = f32_to_bf16_rn(ar0[i]);                   \
      float lo = ar0[i] - bf16_to_f32(hb);                          \
      hv0[i] = (short)hb; lv0[i] = (short)f32_to_bf16_rn(lo);       \
      hb = f32_to_bf16_rn(ar1[i]);                                  \
      lo = ar1[i] - bf16_to_f32(hb);                                \
      hv1[i] = (short)hb; lv1[i] = (short)f32_to_bf16_rn(lo);       \
    }                                                               \
    int off0 = lds_off(srow, sslot);                                \
    int off1 = lds_off(srow + 64, sslot);                           \
    *(short8v*)&Ah[BUF][off0] = hv0; *(short8v*)&Al[BUF][off0] = lv0; \
    *(short8v*)&Ah[BUF][off1] = hv1; *(short8v*)&Al[BUF][off1] = lv1; \
  } while (0)

#define LOAD_B(K0, BH, BL)                                          \
  do {                                                              \
    _Pragma("unroll")                                               \
    for (int ni = 0; ni < 4; ni++) {                                \
      int col = wc * 64 + ni * 16 + fr;                             \
      size_t ba = (size_t)col * KP + (K0) + ko * 8;                 \
      BH[ni] = *(const short8v*)&BhT[ba];                           \
      BL[ni] = *(const short8v*)&BlT[ba];                           \
    }                                                               \
  } while (0)

#define COMPUTE(BUF, BH, BL)                                                                             \
  do {                                                                                                   \
    short8v afh[4], afl[4];                                                                              \
    _Pragma("unroll")                                                                                    \
    for (int mi = 0; mi < 4; mi++) {                                                                     \
      int off = lds_off(wr * 64 + mi * 16 + fr, ko);                                                     \
      afh[mi] = *(short8v*)&Ah[BUF][off];                                                                \
      afl[mi] = *(short8v*)&Al[BUF][off];                                                                \
    }                                                                                                    \
    _Pragma("unroll")                                                                                    \
    for (int mi = 0; mi < 4; mi++)                                                                       \
      _Pragma("unroll")                                                                                  \
      for (int ni = 0; ni < 4; ni++) {                                                                   \
        acc[mi][ni] = __builtin_amdgcn_mfma_f32_16x16x32_bf16(afh[mi], BH[ni], acc[mi][ni], 0, 0, 0);    \
        acc[mi][ni] = __builtin_amdgcn_mfma_f32_16x16x32_bf16(afl[mi], BH[ni], acc[mi][ni], 0, 0, 0);    \
        acc[mi][ni] = __builtin_amdgcn_mfma_f32_16x16x32_bf16(afh[mi], BL[ni], acc[mi][ni], 0, 0, 0);    \
      }                                                                                                  \
  } while (0)

  // prologue: stage step 0
  LOAD_A(0);
  LOAD_B(0, bh0, bl0);
  CONV_A(0);
  __syncthreads();

  // steady state: steps 0..13 (prefetch always valid, fast-path loads)
  for (int k = 0; k < 14; k += 2) {
    LOAD_A((k + 1) * 32);
    LOAD_B((k + 1) * 32, bh1, bl1);
    COMPUTE(0, bh0, bl0);
    CONV_A(1);
    __syncthreads();
    LOAD_A((k + 2) * 32);
    LOAD_B((k + 2) * 32, bh0, bl0);
    COMPUTE(1, bh1, bl1);
    CONV_A(0);
    __syncthreads();
  }
  // step 14 (+ prefetch boundary step 15)
  LOAD_A(480);
  LOAD_B(480, bh1, bl1);
  COMPUTE(0, bh0, bl0);
  CONV_A(1);
  __syncthreads();
  // step 15
  COMPUTE(1, bh1, bl1);

#undef LOAD_A
#undef CONV_A
#undef LOAD_B
#undef COMPUTE

  // epilogue: C/D layout col=lane&15, row=(lane>>4)*4+reg; store fp16
#pragma unroll
  for (int mi = 0; mi < 4; mi++) {
#pragma unroll
    for (int r = 0; r < 4; r++) {
      int grow = bm + wr * 64 + mi * 16 + ko * 4 + r;
      if (grow < NNODES) {
#pragma unroll
        for (int ni = 0; ni < 4; ni++) {
          int col = wc * 64 + ni * 16 + fr;
          z1h[(size_t)grow * HID + col] = __float2half(acc[mi][ni][r]);
        }
      }
    }
  }
}

// ---------------- el/er for layer 1 (from fp16 z1) ----------------
__global__ __launch_bounds__(128) void attn_lr1_kernel(const __half* __restrict__ z1h,
                                                       const float* __restrict__ al,
                                                       const float* __restrict__ ar,
                                                       float* __restrict__ el,
                                                       float* __restrict__ er) {
  int n = blockIdx.x, t = threadIdx.x;
  float v = __half2float(z1h[(size_t)n * HID + t]);
  float l = v * al[t];
  float r = v * ar[t];
#pragma unroll
  for (int m = 16; m >= 1; m >>= 1) {
    l += __shfl_xor(l, m);
    r += __shfl_xor(r, m);
  }
  if ((t & 31) == 0) {
    el[n * NH + (t >> 5)] = l;
    er[n * NH + (t >> 5)] = r;
  }
}

// ---------------- CSR offsets from sorted dst ----------------
__global__ void csr_offsets_kernel(const int* __restrict__ dst, int E, int* __restrict__ off) {
  int n = blockIdx.x * blockDim.x + threadIdx.x;
  if (n > NNODES) return;
  int lo = 0, hi = E;
  while (lo < hi) {
    int mid = (lo + hi) >> 1;
    if (dst[mid] < n) lo = mid + 1; else hi = mid;
  }
  off[n] = lo;
}

// ---------------- layer-1: wave-per-node online-softmax + fp16 aggregation ----------------
__global__ __launch_bounds__(256) void gat1_agg_kernel(const __half* __restrict__ z1h,
                                                       const float* __restrict__ el,
                                                       const float* __restrict__ er,
                                                       const int* __restrict__ src,
                                                       const int* __restrict__ off,
                                                       const float* __restrict__ b1,
                                                       float* __restrict__ h1) {
  int wid = threadIdx.x >> 6, lane = threadIdx.x & 63;
  int n = blockIdx.x * 4 + wid;
  if (n >= NNODES) return;
  __shared__ float p_sh[4][64 * 4];

  int start = off[n], end = off[n + 1];
  const float4* el4 = reinterpret_cast<const float4*>(el);
  float4 er4 = reinterpret_cast<const float4*>(er)[n];
  const __half2* zp = reinterpret_cast<const __half2*>(z1h);

  int c = lane;
  int head = c >> 4;
  float2 acc = make_float2(0.f, 0.f);
  float m0 = -INFINITY, m1 = -INFINITY, m2 = -INFINITY, m3 = -INFINITY;
  float d0 = 0.f, d1 = 0.f, d2 = 0.f, d3 = 0.f;

  for (int base = start; base < end; base += 64) {
    int cnt = min(64, end - base);
    int sr = 0;
    float e0 = -INFINITY, e1 = -INFINITY, e2 = -INFINITY, e3 = -INFINITY;
    if (lane < cnt) {
      sr = src[base + lane];
      float4 x = el4[sr];
      e0 = lrelu(x.x + er4.x);
      e1 = lrelu(x.y + er4.y);
      e2 = lrelu(x.z + er4.z);
      e3 = lrelu(x.w + er4.w);
    }
    float x0 = e0, x1 = e1, x2 = e2, x3 = e3;
#pragma unroll
    for (int msk = 32; msk >= 1; msk >>= 1) {
      x0 = fmaxf(x0, __shfl_xor(x0, msk));
      x1 = fmaxf(x1, __shfl_xor(x1, msk));
      x2 = fmaxf(x2, __shfl_xor(x2, msk));
      x3 = fmaxf(x3, __shfl_xor(x3, msk));
    }
    float n0 = fmaxf(m0, x0), n1 = fmaxf(m1, x1), n2 = fmaxf(m2, x2), n3 = fmaxf(m3, x3);
    float p0 = 0.f, p1 = 0.f, p2 = 0.f, p3 = 0.f;
    if (lane < cnt) {
      p0 = __expf(e0 - n0); p1 = __expf(e1 - n1);
      p2 = __expf(e2 - n2); p3 = __expf(e3 - n3);
    }
    float s0 = p0, s1 = p1, s2 = p2, s3 = p3;
#pragma unroll
    for (int msk = 32; msk >= 1; msk >>= 1) {
      s0 += __shfl_xor(s0, msk);
      s1 += __shfl_xor(s1, msk);
      s2 += __shfl_xor(s2, msk);
      s3 += __shfl_xor(s3, msk);
    }
    float sc0 = __expf(m0 - n0), sc1 = __expf(m1 - n1);
    float sc2 = __expf(m2 - n2), sc3 = __expf(m3 - n3);
    d0 = d0 * sc0 + s0; d1 = d1 * sc1 + s1;
    d2 = d2 * sc2 + s2; d3 = d3 * sc3 + s3;
    m0 = n0; m1 = n1; m2 = n2; m3 = n3;
    float sch = sel4(sc0, sc1, sc2, sc3, head);
    acc.x *= sch;
    acc.y *= sch;
    *(float4*)&p_sh[wid][lane * 4] = make_float4(p0, p1, p2, p3);
    __builtin_amdgcn_wave_barrier();
    int i = 0;
    for (; i + 1 < cnt; i += 2) {
      int sa = __shfl(sr, i), sb = __shfl(sr, i + 1);
      float pa = p_sh[wid][i * 4 + head];
      float pb = p_sh[wid][(i + 1) * 4 + head];
      float2 va = __half22float2(zp[(size_t)sa * 64 + c]);
      float2 vb = __half22float2(zp[(size_t)sb * 64 + c]);
      acc.x = fmaf(pa, va.x, acc.x); acc.y = fmaf(pa, va.y, acc.y);
      acc.x = fmaf(pb, vb.x, acc.x); acc.y = fmaf(pb, vb.y, acc.y);
    }
    if (i < cnt) {
      int sa = __shfl(sr, i);
      float pa = p_sh[wid][i * 4 + head];
      float2 va = __half22float2(zp[(size_t)sa * 64 + c]);
      acc.x = fmaf(pa, va.x, acc.x); acc.y = fmaf(pa, va.y, acc.y);
    }
    __builtin_amdgcn_wave_barrier();
  }

  float dh = sel4(d0, d1, d2, d3, head);
  float inv = 1.f / fmaxf(dh, 1e-9f);
  float2 bias = reinterpret_cast<const float2*>(b1)[c];
  float v0 = acc.x * inv + bias.x;
  float v1 = acc.y * inv + bias.y;
  v0 = v0 > 0.f ? v0 : __expf(v0) - 1.f;
  v1 = v1 > 0.f ? v1 : __expf(v1) - 1.f;
  reinterpret_cast<float2*>(h1)[(size_t)n * 64 + c] = make_float2(v0, v1);
}

// ---------------- layer-2 projection: z2el = (z2[0..2], el2); er2 separate ----------------
__global__ __launch_bounds__(128) void proj2_kernel(const float* __restrict__ h1,
                                                    const float* __restrict__ W2,
                                                    const float* __restrict__ al2,
                                                    const float* __restrict__ ar2,
                                                    float4* __restrict__ z2el,
                                                    float* __restrict__ er2) {
  int n = blockIdx.x, t = threadIdx.x;
  float hv = h1[(size_t)n * HID + t];
  float p0 = hv * W2[t * 3 + 0];
  float p1 = hv * W2[t * 3 + 1];
  float p2 = hv * W2[t * 3 + 2];
#pragma unroll
  for (int msk = 32; msk >= 1; msk >>= 1) {
    p0 += __shfl_xor(p0, msk);
    p1 += __shfl_xor(p1, msk);
    p2 += __shfl_xor(p2, msk);
  }
  __shared__ float red[2][3];
  if ((t & 63) == 0) {
    red[t >> 6][0] = p0; red[t >> 6][1] = p1; red[t >> 6][2] = p2;
  }
  __syncthreads();
  if (t == 0) {
    float a = red[0][0] + red[1][0];
    float b = red[0][1] + red[1][1];
    float c = red[0][2] + red[1][2];
    z2el[n] = make_float4(a, b, c, a * al2[0] + b * al2[1] + c * al2[2]);
    er2[n] = a * ar2[0] + b * ar2[1] + c * ar2[2];
  }
}

// ---------------- layer-2: wave-per-node single-pass softmax + aggregation ----------------
__global__ __launch_bounds__(256) void gat2_agg_kernel(const float4* __restrict__ z2el,
                                                       const float* __restrict__ er2,
                                                       const int* __restrict__ src,
                                                       const int* __restrict__ off,
                                                       const float* __restrict__ b2,
                                                       float* __restrict__ out) {
  int wid = threadIdx.x >> 6, lane = threadIdx.x & 63;
  int n = blockIdx.x * 4 + wid;
  if (n >= NNODES) return;
  int start = off[n], end = off[n + 1];
  float ern = er2[n];
  float m_run = -INFINITY, d_run = 0.f;
  float a0 = 0.f, a1 = 0.f, a2 = 0.f;
  for (int base = start; base < end; base += 64) {
    int cnt = min(64, end - base);
    float4 z4 = make_float4(0.f, 0.f, 0.f, 0.f);
    float e = -INFINITY;
    if (lane < cnt) {
      z4 = z2el[src[base + lane]];
      e = lrelu(z4.w + ern);
    }
    float mx = e;
#pragma unroll
    for (int msk = 32; msk >= 1; msk >>= 1) mx = fmaxf(mx, __shfl_xor(mx, msk));
    float m_new = fmaxf(m_run, mx);
    float p = (lane < cnt) ? __expf(e - m_new) : 0.f;
    float sm = p;
#pragma unroll
    for (int msk = 32; msk >= 1; msk >>= 1) sm += __shfl_xor(sm, msk);
    float scale = __expf(m_run - m_new);
    d_run = d_run * scale + sm;
    a0 = a0 * scale + p * z4.x;
    a1 = a1 * scale + p * z4.y;
    a2 = a2 * scale + p * z4.z;
    m_run = m_new;
  }
#pragma unroll
  for (int msk = 32; msk >= 1; msk >>= 1) {
    a0 += __shfl_xor(a0, msk);
    a1 += __shfl_xor(a1, msk);
    a2 += __shfl_xor(a2, msk);
  }
  if (lane == 0) {
    float inv = 1.f / fmaxf(d_run, 1e-9f);
    out[n * 3 + 0] = a0 * inv + b2[0];
    out[n * 3 + 1] = a1 * inv + b2[1];
    out[n * 3 + 2] = a2 * inv + b2[2];
  }
}

extern "C" void kernel_launch(void* const* d_in, const int* in_sizes, int n_in,
                              void* d_out, int out_size, void* d_ws, size_t ws_size,
                              hipStream_t stream) {
  const float* features = (const float*)d_in[0];
  const int* src = (const int*)d_in[1];
  const int* dst = (const int*)d_in[2];
  const float* W1 = (const float*)d_in[3];
  const float* al1 = (const float*)d_in[4];
  const float* ar1 = (const float*)d_in[5];
  const float* b1 = (const float*)d_in[6];
  const float* W2 = (const float*)d_in[7];
  const float* al2 = (const float*)d_in[8];
  const float* ar2 = (const float*)d_in[9];
  const float* b2 = (const float*)d_in[10];
  float* out = (float*)d_out;
  int E = in_sizes[1];

  char* ws = (char*)d_ws;
  size_t o = 0;
  __half* z1h = (__half*)(ws + o); o += (size_t)NNODES * HID * 2;
  float* h1 = (float*)(ws + o);    o += (size_t)NNODES * HID * 4;
  float* el1 = (float*)(ws + o);   o += (size_t)NNODES * NH * 4;
  float* er1 = (float*)(ws + o);   o += (size_t)NNODES * NH * 4;
  float4* z2el = (float4*)(ws + o); o += (size_t)NNODES * 16;
  float* er2 = (float*)(ws + o);   o += (size_t)NNODES * 4;
  short* BhT = (short*)(ws + o);   o += (size_t)HID * KP * 2;
  short* BlT = (short*)(ws + o);   o += (size_t)HID * KP * 2;
  int* off = (int*)(ws + o);       o += (size_t)(NNODES + 1) * 4;

  convert_w1_kernel<<<256, 256, 0, stream>>>(W1, BhT, BlT);
  gemm1_mfma_kernel<<<(NNODES + 127) / 128, 256, 0, stream>>>(features, BhT, BlT, z1h);
  attn_lr1_kernel<<<NNODES, 128, 0, stream>>>(z1h, al1, ar1, el1, er1);
  csr_offsets_kernel<<<(NNODES + 1 + 255) / 256, 256, 0, stream>>>(dst, E, off);
  gat1_agg_kernel<<<(NNODES + 3) / 4, 256, 0, stream>>>(z1h, el1, er1, src, off, b1, h1);
  proj2_kernel<<<NNODES, 128, 0, stream>>>(h1, W2, al2, ar2, z2el, er2);
  gat2_agg_kernel<<<(NNODES + 3) / 4, 256, 0, stream>>>(z2el, er2, src, off, b2, out);
}